// Round 8
// baseline (302.736 us; speedup 1.0000x reference)
//
#include <hip/hip_runtime.h>

// Problem constants
#define B_     16384
#define TD     512     // T*D
#define HID    128
#define LAT    512     // N_TOKENS*CODE_DIM
#define NCODES 512
#define CDIM   64
#define NTOK   8
#define EPS    1e-5f
#define MARGIN 0.02f   // ~10x worst-case approx-distance error (2.6e-3) post-LN

typedef unsigned short u16;
typedef unsigned int   u32;
typedef short bf16x8 __attribute__((ext_vector_type(8)));   // 8 bf16 = 4 VGPR (MFMA A/B frag)
typedef float f32x4  __attribute__((ext_vector_type(4)));   // MFMA C/D frag

__device__ __forceinline__ u16 bf16_rn(float f){
    u32 u = __float_as_uint(f);
    return (u16)((u + 0x7fffu + ((u >> 16) & 1u)) >> 16);   // round-nearest-even
}
__device__ __forceinline__ float bf16_f(u16 h){ return __uint_as_float(((u32)h) << 16); }
__device__ __forceinline__ void split2(float f, u16& hi, u16& lo){
    hi = bf16_rn(f);
    lo = bf16_rn(f - bf16_f(hi));     // residual: |a - hi - lo| <= ~2^-18 |a|
}
#define MFMA16(a,b,c) __builtin_amdgcn_mfma_f32_16x16x32_bf16((a),(b),(c),0,0,0)

// ---------------------------------------------------------------------------
// Prep: c2[c] = ||codebook[c]||^2 (fp32 exact)
// ---------------------------------------------------------------------------
__global__ void c2_kernel(const float* __restrict__ cb, float* __restrict__ c2) {
    int c = blockIdx.x;
    int d = threadIdx.x;            // 64 threads = 1 wave
    float v = cb[c * CDIM + d];
    float s = v * v;
#pragma unroll
    for (int m = 32; m >= 1; m >>= 1) s += __shfl_xor(s, m, 64);
    if (d == 0) c2[c] = s;
}

// ---------------------------------------------------------------------------
// Prep: transpose+split W[K][N] -> hi/lo planes [N][K] (bf16)
// ---------------------------------------------------------------------------
__global__ void tsplit_kernel(const float* __restrict__ W, u16* __restrict__ hi,
                              u16* __restrict__ lo, int N, int kshift){
    int id = blockIdx.x * 256 + threadIdx.x;    // over N*K output elems
    int K = 1 << kshift;
    int n = id >> kshift, k = id & (K - 1);
    u16 h, l2; split2(W[(size_t)k * N + n], h, l2);
    hi[id] = h; lo[id] = l2;
}
// Prep: split codebook [512][64] (no transpose)
__global__ void csplit_kernel(const float* __restrict__ C, u16* __restrict__ hi,
                              u16* __restrict__ lo){
    int id = blockIdx.x * 256 + threadIdx.x;
    u16 h, l2; split2(C[id], h, l2);
    hi[id] = h; lo[id] = l2;
}
// Prep: P[c][t][j] = sum_k cb[c][k] * dec_w1[t*64+k][j]   (replaces dec GEMM1)
__global__ void pprep_kernel(const float* __restrict__ cb, const float* __restrict__ dw1,
                             float* __restrict__ P){
    int c = blockIdx.x, t = blockIdx.y, j = threadIdx.x;
    const float* wp = dw1 + (size_t)t * 64 * HID + j;
    const float* cp = cb + (size_t)c * CDIM;
    float acc = 0.f;
#pragma unroll
    for (int k = 0; k < 64; ++k) acc = fmaf(cp[k], wp[(size_t)k * HID], acc);
    P[((size_t)c * 8 + t) * HID + j] = acc;
}

// ---------------------------------------------------------------------------
// ENCODER GEMM1 (fp32 reference numerics class): baseline VALU fp32 tiled GEMM.
// [byte-identical to the R2/R7 passing kernel — do not touch]
// ---------------------------------------------------------------------------
template<bool RELU, bool LN>
__launch_bounds__(256)
__global__ void gemm_kernel(const float* __restrict__ A, const float* __restrict__ W,
                            const float* __restrict__ bias,
                            float* __restrict__ C,
                            int M, int N, int K) {
    constexpr int BM = 64, BN = 64, BK = 32;
    __shared__ float As[BK][BM + 4];   // transposed: As[k][m]
    __shared__ float Ws[BK][BN + 4];

    const int tid = threadIdx.x;
    const int tx  = tid & 15;          // 0..15 (cols)
    const int ty  = tid >> 4;          // 0..15 (rows)
    const int m0  = blockIdx.x * BM;
    const int n0  = blockIdx.y * BN;

    float acc[4][4] = {};

    for (int k0 = 0; k0 < K; k0 += BK) {
        {
            int r  = tid >> 3;               // 0..31
            int c4 = (tid & 7) * 4;          // 0..28
#pragma unroll
            for (int h = 0; h < 2; ++h) {
                int rr = r + h * 32;
                float4 v = *(const float4*)&A[(size_t)(m0 + rr) * K + k0 + c4];
                As[c4 + 0][rr] = v.x; As[c4 + 1][rr] = v.y;
                As[c4 + 2][rr] = v.z; As[c4 + 3][rr] = v.w;
            }
        }
        {
            int r  = tid >> 4;               // 0..15
            int c4 = (tid & 15) * 4;         // 0..60
#pragma unroll
            for (int h = 0; h < 2; ++h) {
                int rr = r + h * 16;
                float4 v = *(const float4*)&W[(size_t)(k0 + rr) * N + n0 + c4];
                *(float4*)&Ws[rr][c4] = v;
            }
        }
        __syncthreads();

#pragma unroll
        for (int kk = 0; kk < BK; ++kk) {
            float4 a = *(const float4*)&As[kk][ty * 4];
            float4 b = *(const float4*)&Ws[kk][tx * 4];
            float av[4] = {a.x, a.y, a.z, a.w};
            float bv[4] = {b.x, b.y, b.z, b.w};
#pragma unroll
            for (int i = 0; i < 4; ++i)
#pragma unroll
                for (int j = 0; j < 4; ++j)
                    acc[i][j] = fmaf(av[i], bv[j], acc[i][j]);
        }
        __syncthreads();
    }

    float bv[4];
#pragma unroll
    for (int j = 0; j < 4; ++j) bv[j] = bias[n0 + tx * 4 + j];

#pragma unroll
    for (int i = 0; i < 4; ++i) {
        float c[4];
#pragma unroll
        for (int j = 0; j < 4; ++j) {
            c[j] = acc[i][j] + bv[j];
            if (RELU) c[j] = fmaxf(c[j], 0.0f);
        }
        if (LN) {
            float s  = c[0] + c[1] + c[2] + c[3];
            float ss = c[0]*c[0] + c[1]*c[1] + c[2]*c[2] + c[3]*c[3];
#pragma unroll
            for (int m = 1; m <= 8; m <<= 1) {
                s  += __shfl_xor(s,  m, 64);
                ss += __shfl_xor(ss, m, 64);
            }
            float mean = s * (1.0f / 64.0f);
            float var  = ss * (1.0f / 64.0f) - mean * mean;
            float rstd = rsqrtf(var + EPS);
#pragma unroll
            for (int j = 0; j < 4; ++j) c[j] = (c[j] - mean) * rstd;
        }
        size_t row = (size_t)(m0 + ty * 4 + i);
        *(float4*)&C[row * N + n0 + tx * 4] = make_float4(c[0], c[1], c[2], c[3]);
    }
}

// ---------------------------------------------------------------------------
// ENCODER GEMM2, 8x8 microtile (BM=BN=128, BK=32, 256 thr, grid 128x4=512).
// Matmul accumulation is BIT-IDENTICAL to baseline per output element (strict
// k-ascending, single fmaf accumulator). LN over the 64-col token group =
// 8 lanes x 8 local cols (shfl masks 1,2,4); 1-ulp-class reorder vs baseline,
// same risk class as our (passing) deviation vs the JAX reference.
// FMA:LDS intensity 4 FMA/float (2x baseline).
// ---------------------------------------------------------------------------
__launch_bounds__(256)
__global__ void gemm8_ln(const float* __restrict__ A, const float* __restrict__ W,
                         const float* __restrict__ bias, float* __restrict__ C,
                         int M, int N, int K) {
    __shared__ float As[32][128 + 4];   // transposed: As[k][m]
    __shared__ float Ws[32][128 + 4];   // Ws[k][n]

    const int tid = threadIdx.x;
    const int tx  = tid & 15;           // 0..15, cols tx*8..+7
    const int ty  = tid >> 4;           // 0..15, rows ty*8..+7
    const int m0  = blockIdx.x * 128;
    const int n0  = blockIdx.y * 128;

    float acc[8][8] = {};

    for (int k0 = 0; k0 < K; k0 += 32) {
        // A tile: 128 rows x 32 k, transposed. thread -> (row=tid>>1, 16-float half)
        {
            int r   = tid >> 1;
            int c16 = (tid & 1) * 16;
#pragma unroll
            for (int q = 0; q < 4; ++q) {
                float4 v = *(const float4*)&A[(size_t)(m0 + r) * K + k0 + c16 + q * 4];
                As[c16 + q * 4 + 0][r] = v.x; As[c16 + q * 4 + 1][r] = v.y;
                As[c16 + q * 4 + 2][r] = v.z; As[c16 + q * 4 + 3][r] = v.w;
            }
        }
        // W tile: 32 k x 128 n, direct
        {
#pragma unroll
            for (int h = 0; h < 4; ++h) {
                int idx = tid + 256 * h;          // 0..1023 float4 groups
                int r = idx >> 5, c4 = (idx & 31) * 4;
                float4 v = *(const float4*)&W[(size_t)(k0 + r) * N + n0 + c4];
                *(float4*)&Ws[r][c4] = v;
            }
        }
        __syncthreads();

#pragma unroll
        for (int kk = 0; kk < 32; ++kk) {
            float4 a0 = *(const float4*)&As[kk][ty * 8];
            float4 a1 = *(const float4*)&As[kk][ty * 8 + 4];
            float4 b0 = *(const float4*)&Ws[kk][tx * 8];
            float4 b1 = *(const float4*)&Ws[kk][tx * 8 + 4];
            float av[8] = {a0.x, a0.y, a0.z, a0.w, a1.x, a1.y, a1.z, a1.w};
            float bv[8] = {b0.x, b0.y, b0.z, b0.w, b1.x, b1.y, b1.z, b1.w};
#pragma unroll
            for (int i = 0; i < 8; ++i)
#pragma unroll
                for (int j = 0; j < 8; ++j)
                    acc[i][j] = fmaf(av[i], bv[j], acc[i][j]);
        }
        __syncthreads();
    }

    float bv[8];
#pragma unroll
    for (int j = 0; j < 8; ++j) bv[j] = bias[n0 + tx * 8 + j];

#pragma unroll
    for (int i = 0; i < 8; ++i) {
        float c[8];
#pragma unroll
        for (int j = 0; j < 8; ++j) c[j] = acc[i][j] + bv[j];
        // LN over the 64-col token: this thread's 8 cols + 8-lane tree
        // (lanes l, l^1, l^2, l^4 share ty and tx>>3 -> same row, same token)
        float s  = 0.f, ss = 0.f;
#pragma unroll
        for (int j = 0; j < 8; ++j) { s += c[j]; ss += c[j] * c[j]; }
#pragma unroll
        for (int mk = 1; mk <= 4; mk <<= 1) {
            s  += __shfl_xor(s,  mk, 64);
            ss += __shfl_xor(ss, mk, 64);
        }
        float mean = s * (1.0f / 64.0f);
        float var  = ss * (1.0f / 64.0f) - mean * mean;
        float rstd = rsqrtf(var + EPS);
#pragma unroll
        for (int j = 0; j < 8; ++j) c[j] = (c[j] - mean) * rstd;

        size_t row = (size_t)(m0 + ty * 8 + i);
        *(float4*)&C[row * N + n0 + tx * 8]     = make_float4(c[0], c[1], c[2], c[3]);
        *(float4*)&C[row * N + n0 + tx * 8 + 4] = make_float4(c[4], c[5], c[6], c[7]);
    }
}

// ---------------------------------------------------------------------------
// DECODER GEMM2: split-bf16 MFMA GEMM (3-pass), pre-split planes [proven R5-R7]
// ---------------------------------------------------------------------------
__launch_bounds__(256, 2)
__global__ void gemm_split(const u16* __restrict__ Ahi, const u16* __restrict__ Alo,
                           const u16* __restrict__ Bhi, const u16* __restrict__ Blo,
                           const float* __restrict__ bias,
                           float* __restrict__ Of,
                           int M, int N, int K)
{
    constexpr int BM = 128;
    __shared__ uint4 As[2][BM * 4];
    __shared__ uint4 Bs[2][128 * 4];

    const int tid = threadIdx.x;
    const int wid = tid >> 6, l = tid & 63, ln = l & 15, kg = l >> 4;
    const int mw = wid >> 1, nw = wid & 1;
    const int m0 = blockIdx.x * BM, n0 = blockIdx.y * 128;
    const int swz = (ln >> 1) & 3;

    f32x4 acc[4][4];
#pragma unroll
    for (int i = 0; i < 4; ++i)
#pragma unroll
        for (int j = 0; j < 4; ++j) acc[i][j] = (f32x4){0.f, 0.f, 0.f, 0.f};

    uint4 ra[4], rb[4];
    auto gload = [&](int k0){
#pragma unroll
        for (int h = 0; h < 4; ++h){
            int idx = tid + 256 * h; int r = idx >> 3, pl = (idx >> 2) & 1, c = idx & 3;
            ra[h] = *(const uint4*)((pl ? Alo : Ahi) + (size_t)(m0 + r) * K + k0 + c * 8);
        }
#pragma unroll
        for (int h = 0; h < 4; ++h){
            int idx = tid + 256 * h; int r = idx >> 3, pl = (idx >> 2) & 1, c = idx & 3;
            rb[h] = *(const uint4*)((pl ? Blo : Bhi) + (size_t)(n0 + r) * K + k0 + c * 8);
        }
    };
    auto lstore = [&](){
#pragma unroll
        for (int h = 0; h < 4; ++h){
            int idx = tid + 256 * h; int r = idx >> 3, pl = (idx >> 2) & 1, c = idx & 3;
            As[pl][r * 4 + (c ^ ((r >> 1) & 3))] = ra[h];
        }
#pragma unroll
        for (int h = 0; h < 4; ++h){
            int idx = tid + 256 * h; int r = idx >> 3, pl = (idx >> 2) & 1, c = idx & 3;
            Bs[pl][r * 4 + (c ^ ((r >> 1) & 3))] = rb[h];
        }
    };

    gload(0);
    for (int k0 = 0; k0 < K; k0 += 32){
        if (k0) __syncthreads();
        lstore();
        __syncthreads();
        if (k0 + 32 < K) gload(k0 + 32);

        bf16x8 af[4][2], bfr[4][2];
#pragma unroll
        for (int mi = 0; mi < 4; ++mi){
            int r = mw * 64 + mi * 16 + ln;
            af[mi][0] = *(bf16x8*)&As[0][r * 4 + (kg ^ swz)];
            af[mi][1] = *(bf16x8*)&As[1][r * 4 + (kg ^ swz)];
        }
#pragma unroll
        for (int ni = 0; ni < 4; ++ni){
            int r = nw * 64 + ni * 16 + ln;
            bfr[ni][0] = *(bf16x8*)&Bs[0][r * 4 + (kg ^ swz)];
            bfr[ni][1] = *(bf16x8*)&Bs[1][r * 4 + (kg ^ swz)];
        }
#pragma unroll
        for (int mi = 0; mi < 4; ++mi)
#pragma unroll
            for (int ni = 0; ni < 4; ++ni){
                acc[mi][ni] = MFMA16(af[mi][0], bfr[ni][0], acc[mi][ni]);
                acc[mi][ni] = MFMA16(af[mi][0], bfr[ni][1], acc[mi][ni]);
                acc[mi][ni] = MFMA16(af[mi][1], bfr[ni][0], acc[mi][ni]);
            }
    }

    float bv[4];
#pragma unroll
    for (int ni = 0; ni < 4; ++ni) bv[ni] = bias[n0 + nw * 64 + ni * 16 + ln];
#pragma unroll
    for (int mi = 0; mi < 4; ++mi)
#pragma unroll
        for (int r = 0; r < 4; ++r){
            size_t row = (size_t)(m0 + mw * 64 + mi * 16 + kg * 4 + r);
#pragma unroll
            for (int ni = 0; ni < 4; ++ni)
                Of[row * N + n0 + nw * 64 + ni * 16 + ln] = acc[mi][ni][r] + bv[ni];
        }
}

// ---------------------------------------------------------------------------
// VQ v4 = R2's measured-107.8us vq_kernel2 core, minus the dead zq_ws store,
// minus the P-tail (now a separate kernel). Everything else byte-identical.
// ---------------------------------------------------------------------------
__launch_bounds__(256, 2)
__global__ void vq_kernel4(const float* __restrict__ zln,
                           const u16* __restrict__ Chi, const u16* __restrict__ Clo,
                           const float* __restrict__ cbf, const float* __restrict__ c2,
                           float* __restrict__ zq_o, float* __restrict__ idx_o)
{
    __shared__ uint4 Az[2][64 * 8];     // z tile planes, swizzle ch ^ (row&7)
    __shared__ uint4 Bz[2][128 * 8];    // codebook chunk planes
    __shared__ float c2s[512];
    __shared__ float cB1[4][64], cB2[4][64];
    __shared__ int   cI1[4][64];
    __shared__ int   fI[64];
    __shared__ float zf[64];
    __shared__ int   nflag;
    __shared__ int   flagR[64];
    __shared__ float wB[4];
    __shared__ int   wI[4];

    const int tid = threadIdx.x;
    const int wid = tid >> 6, l = tid & 63, ln = l & 15, kg = l >> 4;
    const int m0 = blockIdx.x * 64;

    // stage z tile: on-the-fly fp32 -> bf16 hi/lo split
#pragma unroll
    for (int h = 0; h < 4; ++h){
        int idx = tid + 256 * h;         // 1024 quarter-rows of 4 dims
        int r = idx >> 4, q = idx & 15;
        float4 v = *(const float4*)&zln[(size_t)(m0 + r) * CDIM + q * 4];
        u16 hs[4] __attribute__((aligned(8)));
        u16 ls[4] __attribute__((aligned(8)));
        split2(v.x, hs[0], ls[0]); split2(v.y, hs[1], ls[1]);
        split2(v.z, hs[2], ls[2]); split2(v.w, hs[3], ls[3]);
        int c = q >> 1, half = q & 1;
        int ch = c ^ (r & 7);
        ((uint2*)&Az[0][r * 8 + ch])[half] = *(const uint2*)hs;
        ((uint2*)&Az[1][r * 8 + ch])[half] = *(const uint2*)ls;
    }
    c2s[tid] = c2[tid]; c2s[tid + 256] = c2[tid + 256];
    if (tid == 0) nflag = 0;
    // stage codebook chunk 0
#pragma unroll
    for (int h = 0; h < 8; ++h){
        int idx = tid + 256 * h; int r = idx >> 4, pl = (idx >> 3) & 1, c = idx & 7;
        const u16* p = (pl ? Clo : Chi) + (size_t)r * CDIM + c * 8;
        Bz[pl][r * 8 + (c ^ (r & 7))] = *(const uint4*)p;
    }
    __syncthreads();

    // A fragments (held in registers for all chunks)
    bf16x8 a[4][2][2];                  // [mi][kslice][plane]
#pragma unroll
    for (int mi = 0; mi < 4; ++mi){
        int r = mi * 16 + ln;
#pragma unroll
        for (int ks = 0; ks < 2; ++ks){
            int c = ks * 4 + kg;
            a[mi][ks][0] = *(bf16x8*)&Az[0][r * 8 + (c ^ (r & 7))];
            a[mi][ks][1] = *(bf16x8*)&Az[1][r * 8 + (c ^ (r & 7))];
        }
    }

    float b1[4][4], b2[4][4]; int i1[4][4];
#pragma unroll
    for (int mi = 0; mi < 4; ++mi)
#pragma unroll
        for (int r = 0; r < 4; ++r){ b1[mi][r] = 3.4e38f; b2[mi][r] = 3.4e38f; i1[mi][r] = 0; }

    for (int cc = 0; cc < 4; ++cc){
        bf16x8 b[2][2][2];
#pragma unroll
        for (int ni = 0; ni < 2; ++ni){
            int r = wid * 32 + ni * 16 + ln;
#pragma unroll
            for (int ks = 0; ks < 2; ++ks){
                int c = ks * 4 + kg;
                b[ni][ks][0] = *(bf16x8*)&Bz[0][r * 8 + (c ^ (r & 7))];
                b[ni][ks][1] = *(bf16x8*)&Bz[1][r * 8 + (c ^ (r & 7))];
            }
        }
        f32x4 acc[4][2];
#pragma unroll
        for (int mi = 0; mi < 4; ++mi)
#pragma unroll
            for (int ni = 0; ni < 2; ++ni) acc[mi][ni] = (f32x4){0.f, 0.f, 0.f, 0.f};
#pragma unroll
        for (int mi = 0; mi < 4; ++mi)
#pragma unroll
            for (int ni = 0; ni < 2; ++ni)
#pragma unroll
                for (int ks = 0; ks < 2; ++ks){
                    acc[mi][ni] = MFMA16(a[mi][ks][0], b[ni][ks][0], acc[mi][ni]);
                    acc[mi][ni] = MFMA16(a[mi][ks][0], b[ni][ks][1], acc[mi][ni]);
                    acc[mi][ni] = MFMA16(a[mi][ks][1], b[ni][ks][0], acc[mi][ni]);
                }
#pragma unroll
        for (int mi = 0; mi < 4; ++mi)
#pragma unroll
            for (int ni = 0; ni < 2; ++ni){
                int code = cc * 128 + wid * 32 + ni * 16 + ln;
#pragma unroll
                for (int r = 0; r < 4; ++r){
                    float d = fmaf(-2.f, acc[mi][ni][r], c2s[code]);
                    if (d < b1[mi][r]) { b2[mi][r] = b1[mi][r]; b1[mi][r] = d; i1[mi][r] = code; }
                    else if (d < b2[mi][r]) b2[mi][r] = d;
                }
            }
        if (cc < 3){
            __syncthreads();
#pragma unroll
            for (int h = 0; h < 8; ++h){
                int idx = tid + 256 * h; int r = idx >> 4, pl = (idx >> 3) & 1, c = idx & 7;
                const u16* p = (pl ? Clo : Chi) + (size_t)((cc + 1) * 128 + r) * CDIM + c * 8;
                Bz[pl][r * 8 + (c ^ (r & 7))] = *(const uint4*)p;
            }
            __syncthreads();
        }
    }

    // butterfly over the 16 lanes holding a row's columns (tie -> lower idx)
#pragma unroll
    for (int mi = 0; mi < 4; ++mi)
#pragma unroll
        for (int r = 0; r < 4; ++r){
            float v1 = b1[mi][r], v2 = b2[mi][r]; int ii = i1[mi][r];
#pragma unroll
            for (int mk = 1; mk <= 8; mk <<= 1){
                float o1 = __shfl_xor(v1, mk, 64), o2 = __shfl_xor(v2, mk, 64);
                int   oi = __shfl_xor(ii, mk, 64);
                float n2 = fminf(fmaxf(v1, o1), fminf(v2, o2));   // 2nd-smallest of union
                if (o1 < v1 || (o1 == v1 && oi < ii)){ v1 = o1; ii = oi; }
                v2 = n2;
            }
            if (ln == 0){
                int row = mi * 16 + kg * 4 + r;
                cB1[wid][row] = v1; cB2[wid][row] = v2; cI1[wid][row] = ii;
            }
        }
    __syncthreads();
    if (tid < 64){
        float v1 = cB1[0][tid], v2 = cB2[0][tid]; int ii = cI1[0][tid];
#pragma unroll
        for (int w = 1; w < 4; ++w){
            float o1 = cB1[w][tid], o2 = cB2[w][tid]; int oi = cI1[w][tid];
            float n2 = fminf(fmaxf(v1, o1), fminf(v2, o2));
            if (o1 < v1 || (o1 == v1 && oi < ii)){ v1 = o1; ii = oi; }
            v2 = n2;
        }
        fI[tid] = ii;
        if (v2 - v1 < MARGIN){ int s = atomicAdd(&nflag, 1); flagR[s] = tid; }
    }
    __syncthreads();

    // exact fp32 rescue for ambiguous tokens (reads true fp32 z)
    int nf = nflag;
    for (int f = 0; f < nf; ++f){
        int row = flagR[f];
        if (tid < 64) zf[tid] = zln[(size_t)(m0 + row) * CDIM + tid];
        __syncthreads();
        float bb = 3.4e38f; int bi = 0;
#pragma unroll
        for (int cH = 0; cH < 2; ++cH){
            int cc = tid + 256 * cH;
            const float* cp = cbf + (size_t)cc * CDIM;
            float dot = 0.f;
#pragma unroll
            for (int dd = 0; dd < 64; ++dd) dot = fmaf(zf[dd], cp[dd], dot);
            float d = fmaf(-2.f, dot, c2s[cc]);
            if (d < bb){ bb = d; bi = cc; }     // cc strictly ascending per thread
        }
#pragma unroll
        for (int mk = 1; mk < 64; mk <<= 1){
            float o = __shfl_xor(bb, mk, 64); int oi = __shfl_xor(bi, mk, 64);
            if (o < bb || (o == bb && oi < bi)){ bb = o; bi = oi; }
        }
        if (l == 0){ wB[wid] = bb; wI[wid] = bi; }
        __syncthreads();
        if (tid == 0){
            float v1 = wB[0]; int ii = wI[0];
#pragma unroll
            for (int w = 1; w < 4; ++w)
                if (wB[w] < v1 || (wB[w] == v1 && wI[w] < ii)){ v1 = wB[w]; ii = wI[w]; }
            fI[row] = ii;
        }
        __syncthreads();
    }

    // gather + outputs: 4 threads per row, 16 dims each (fp32, exact)
    {
        int row = tid >> 2, part = tid & 3;
        int ii  = fI[row];
        size_t gr = (size_t)(m0 + row);
        const float* cf = cbf + (size_t)ii * CDIM + part * 16;
        float4 q0 = *(const float4*)(cf + 0),  q1 = *(const float4*)(cf + 4);
        float4 q2 = *(const float4*)(cf + 8),  q3 = *(const float4*)(cf + 12);
        float* zo = zq_o + gr * CDIM + part * 16;
        *(float4*)(zo + 0) = q0; *(float4*)(zo + 4)  = q1;
        *(float4*)(zo + 8) = q2; *(float4*)(zo + 12) = q3;
        if (part == 0) idx_o[gr] = (float)ii;
    }
}

// ---------------------------------------------------------------------------
// h-gather (replaces dec GEMM1): h = relu(b1 + sum_t P[idx_t][t][:]),
// written as pre-split bf16 planes. Block = 8 samples, 32 thr/sample.
// Reads idx from idx_o (global); Ptab is 2MB L2-resident.
// ---------------------------------------------------------------------------
__launch_bounds__(256, 8)
__global__ void hgather_kernel(const float* __restrict__ idx_o,
                               const float* __restrict__ Ptab, const float* __restrict__ db1,
                               u16* __restrict__ h_h, u16* __restrict__ h_l)
{
    __shared__ int fI[64];
    const int tid = threadIdx.x;
    if (tid < 64) fI[tid] = (int)idx_o[(size_t)blockIdx.x * 64 + tid];
    __syncthreads();

    int s  = tid >> 5;                 // 0..7
    int j0 = (tid & 31) * 4;           // 0..124
    float4 hv = *(const float4*)&db1[j0];
#pragma unroll
    for (int t = 0; t < 8; ++t){
        int c = fI[s * 8 + t];
        const float* pp = Ptab + ((size_t)c * 8 + t) * HID + j0;
        float4 p = *(const float4*)pp;
        hv.x += p.x; hv.y += p.y; hv.z += p.z; hv.w += p.w;
    }
    hv.x = fmaxf(hv.x, 0.f); hv.y = fmaxf(hv.y, 0.f);
    hv.z = fmaxf(hv.z, 0.f); hv.w = fmaxf(hv.w, 0.f);
    u16 hh[4] __attribute__((aligned(8)));
    u16 ll[4] __attribute__((aligned(8)));
    split2(hv.x, hh[0], ll[0]); split2(hv.y, hh[1], ll[1]);
    split2(hv.z, hh[2], ll[2]); split2(hv.w, hh[3], ll[3]);
    size_t hrow = ((size_t)blockIdx.x * 8 + s) * HID + j0;
    *(uint2*)&h_h[hrow] = *(const uint2*)hh;
    *(uint2*)&h_l[hrow] = *(const uint2*)ll;
}

// ---------------------------------------------------------------------------
extern "C" void kernel_launch(void* const* d_in, const int* in_sizes, int n_in,
                              void* d_out, int out_size, void* d_ws, size_t ws_size,
                              hipStream_t stream) {
    const float* x      = (const float*)d_in[0];
    const float* enc_w1 = (const float*)d_in[1];
    const float* enc_b1 = (const float*)d_in[2];
    const float* enc_w2 = (const float*)d_in[3];
    const float* enc_b2 = (const float*)d_in[4];
    const float* cbk    = (const float*)d_in[5];
    const float* dec_w1 = (const float*)d_in[6];
    const float* dec_b1 = (const float*)d_in[7];
    const float* dec_w2 = (const float*)d_in[8];
    const float* dec_b2 = (const float*)d_in[9];

    // outputs, all float32, concatenated flat: recon | z_q | indices
    float* out     = (float*)d_out;
    float* recon_o = out;
    float* zq_o    = out + (size_t)B_ * TD;
    float* idx_o   = out + 2 * (size_t)B_ * TD;

    // workspace carve-up
    float* zbuf  = (float*)d_ws;                       // [B,512] fp32 z (post-LN)
    float* hbuf  = zbuf + (size_t)B_ * TD;             // [B,128] fp32 enc hidden / dec h planes
    float* c2buf = hbuf + (size_t)B_ * HID;            // 512 fp32
    float* Ptab  = c2buf + 512;                        // 512*8*128 fp32 = 2 MB
    u16* w = (u16*)(Ptab + (size_t)NCODES * NTOK * HID);
    u16* d2t_h = w; w += 65536;   u16* d2t_l = w; w += 65536;   // dec_w2^T [512][128]
    u16* cb_h  = w; w += 32768;   u16* cb_l  = w; w += 32768;   // codebook [512][64]
    // decoder hidden planes alias hbuf (hbuf dead after encoder GEMM2)
    u16* h_h = (u16*)hbuf;
    u16* h_l = h_h + (size_t)B_ * HID;

    // ---- preps ----
    hipLaunchKernelGGL(tsplit_kernel, dim3(256), dim3(256), 0, stream, dec_w2, d2t_h, d2t_l, TD, 7);
    hipLaunchKernelGGL(csplit_kernel, dim3(128), dim3(256), 0, stream, cbk, cb_h, cb_l);
    hipLaunchKernelGGL(c2_kernel, dim3(NCODES), dim3(64), 0, stream, cbk, c2buf);
    hipLaunchKernelGGL(pprep_kernel, dim3(NCODES, NTOK), dim3(HID), 0, stream, cbk, dec_w1, Ptab);

    // ---- encoder GEMM1 + ReLU (fp32 VALU, baseline): x @ w1 -> hbuf ----
    hipLaunchKernelGGL((gemm_kernel<true, false>), dim3(B_ / 64, HID / 64), dim3(256), 0,
                       stream, x, enc_w1, enc_b1, hbuf, B_, HID, TD);

    // ---- encoder GEMM2 + LN (fp32 VALU, 8x8 microtile): hbuf @ w2 -> zbuf ----
    hipLaunchKernelGGL(gemm8_ln, dim3(B_ / 128, LAT / 128), dim3(256), 0,
                       stream, hbuf, enc_w2, enc_b2, zbuf, B_, LAT, HID);

    // ---- VQ (R2-proven core): zq/idx outputs ----
    hipLaunchKernelGGL(vq_kernel4, dim3(B_ * NTOK / 64), dim3(256), 0, stream,
                       zbuf, cb_h, cb_l, cbk, c2buf, zq_o, idx_o);

    // ---- h-gather (replaces dec GEMM1): idx -> h planes ----
    hipLaunchKernelGGL(hgather_kernel, dim3(B_ / 8), dim3(256), 0, stream,
                       idx_o, Ptab, dec_b1, h_h, h_l);

    // ---- decoder GEMM2 (MFMA): h planes @ dw2 -> recon fp32 ----
    hipLaunchKernelGGL(gemm_split, dim3(B_ / 128, TD / 128), dim3(256), 0, stream,
                       h_h, h_l, d2t_h, d2t_l, dec_b2, recon_o, B_, TD, HID);
}